// Round 1
// 187.604 us; speedup vs baseline: 1.0232x; 1.0232x over previous
//
#include <hip/hip_runtime.h>
#include <stdint.h>

typedef unsigned int uint32;

#define BB 64
#define CC 256
#define OO 256
#define HH 28
#define WW 28
#define HWP 784           // 28*28
#define NWT 589824        // 256*256*9

// ---------------------------------------------------------------------------
// Kernel 1: binarize & bit-pack activations.
// apack[b][p][j] (j=0..7): bit (c%32) of word j=c/32 set iff x[b][c][p] > 0.
// Reads coalesced (64 consecutive p per lane-group); writes are 4B at 32B
// stride but L2 aggregates the 8 j-planes into full lines (FETCH evidence:
// conv sees clean traffic).
// ---------------------------------------------------------------------------
__global__ __launch_bounds__(256) void pack_x_kernel(
    const float* __restrict__ x, uint32* __restrict__ apack) {
  int p = blockIdx.x * 256 + threadIdx.x;
  int j = blockIdx.y;
  int b = blockIdx.z;
  if (p >= HWP) return;
  const float* xp = x + ((size_t)(b * CC + j * 32) * HWP) + p;
  uint32 m = 0;
#pragma unroll
  for (int cc = 0; cc < 32; ++cc) {
    float v = xp[(size_t)cc * HWP];
    m |= ((uint32)(v > 0.0f)) << cc;
  }
  apack[((size_t)b * HWP + p) * 8 + j] = m;
}

// ---------------------------------------------------------------------------
// Kernel 2 (fused, R7): binarize & bit-pack weights + per-o affine tables.
// One block per o: stages all 2304 sums in LDS, packs 72 words, then a
// single lane derives the popcount tables (was a separate 1-block
// whole-GPU ptab_kernel launch — fused to kill a dispatch + serialization).
// sign(w) = sign(m + rv.z) since the rsqrt normalizer is positive.
// wpack[o][tap][j]: tap = (dh+1)*3 + (dw+1), j = c/32, bit = c%32.
// ptabA[o][cls] = alpha*(256*nv_cls + 2*S_cls); cls = hclass*3 + wclass.
// ptabP[o] = {-2*alpha (bits), col0, col2, 0}: virtual zero-column popcounts.
// ---------------------------------------------------------------------------
__global__ __launch_bounds__(256) void pack_w_kernel(
    const float* __restrict__ M, const float* __restrict__ Z,
    const float* __restrict__ rv, const float* __restrict__ alpha,
    uint32* __restrict__ wpack, float* __restrict__ ptabA,
    uint32* __restrict__ ptabP) {
  __shared__ float sacc[2304];
  __shared__ uint32 ww[72];
  const int o = blockIdx.x;
  const int tid = threadIdx.x;
  const size_t base = (size_t)o * 2304;

  float r[8];
#pragma unroll
  for (int k = 0; k < 8; ++k) r[k] = rv[k];

#pragma unroll
  for (int ii = 0; ii < 9; ++ii) {
    int i = tid + ii * 256;  // 2304 = 9*256 exactly, no bounds check
    float s = M[base + i];
#pragma unroll
    for (int k = 0; k < 8; ++k) s += r[k] * Z[(size_t)k * NWT + base + i];
    sacc[i] = s;
  }
  __syncthreads();

  if (tid < 72) {
    int tap = tid % 9;
    int j = tid / 9;
    uint32 m = 0;
#pragma unroll
    for (int cc = 0; cc < 32; ++cc) {
      float v = sacc[(j * 32 + cc) * 9 + tap];
      m |= ((uint32)(v > 0.0f)) << cc;
    }
    ww[tap * 8 + j] = m;
    wpack[(size_t)o * 72 + tap * 8 + j] = m;  // == (o*9+tap)*8+j
  }
  __syncthreads();

  if (tid == 0) {
    int pt[9];
#pragma unroll
    for (int t = 0; t < 9; ++t) {
      int s = 0;
#pragma unroll
      for (int j = 0; j < 8; ++j) s += __popc(ww[t * 8 + j]);
      pt[t] = s;
    }
    int row0 = pt[0] + pt[1] + pt[2], row2 = pt[6] + pt[7] + pt[8];
    int col0 = pt[0] + pt[3] + pt[6], col2 = pt[2] + pt[5] + pt[8];
    float a = alpha[o];
    const int nv[9] = {4, 6, 4, 6, 9, 6, 4, 6, 4};
    int S[9];
    S[0] = row0 + col0 - pt[0]; S[1] = row0; S[2] = row0 + col2 - pt[2];
    S[3] = col0;                S[4] = 0;    S[5] = col2;
    S[6] = row2 + col0 - pt[6]; S[7] = row2; S[8] = row2 + col2 - pt[8];
#pragma unroll
    for (int c = 0; c < 9; ++c)
      ptabA[o * 9 + c] = a * (float)(256 * nv[c] + 2 * S[c]);
    ptabP[o * 4 + 0] = __float_as_uint(-2.0f * a);
    ptabP[o * 4 + 1] = (uint32)col0;
    ptabP[o * 4 + 2] = (uint32)col2;
    ptabP[o * 4 + 3] = 0;
  }
}

// Guaranteed fused popcount-accumulate: T = bitcount(x) + T, one VALU inst.
#define BCNT_ACC(T, x) asm("v_bcnt_u32_b32 %0, %1, %0" : "+v"(T) : "v"(x))

// ---------------------------------------------------------------------------
// Kernel 3 (v5): binary conv — weights in SGPRs, activations in VGPRs,
// 2 output rows per lane, 16 o per block.
//
// R7 change: __launch_bounds__(256, 4) (was (256,8)) + opaque register pin
// on the A tile. R6's profile showed VGPR_Count=24 — too small to hold
// A[4][2] (32 words) — i.e. the 64-VGPR cap made the allocator RE-LOAD the
// activation tile from global (L1) inside every oi iteration (legal: apack
// is __restrict__, loads rematerializable), serialized in tiny chunks.
// That's 128 hidden VMEM loads/lane with vmcnt stalls ≈ the 2.5x gap vs the
// ~33 µs VALU floor. The asm "+v" pin makes the loaded values opaque SSA
// outputs -> non-rematerializable -> they must stay in VGPRs (128 budget).
// Measured occupancy was only 50% anyway, so dropping the residency request
// from 8 to 4 blocks/CU costs nothing (VALU-bound; 6 independent chains).
//
// Core inner op pinned to 2 VALU/word-pair via BCNT_ACC. Horizontal mix
// uses ONE packed shuffle per direction (row0 in low16, row1 in high16;
// column sums <= 768 so the packed add is carry-free). Algebra identical
// to R5/R6 (absmax 0.5 verified): ptab affine epilogue corrects the
// zero-padding; w-edges substitute virtual-zero-column constants.
// ---------------------------------------------------------------------------
__global__ __launch_bounds__(256, 4) void conv_kernel(
    const uint32* __restrict__ apack, const uint32* __restrict__ wpack,
    const float* __restrict__ ptabA, const uint32* __restrict__ ptabP,
    float* __restrict__ out) {
  __shared__ float atab[16 * 9];  // A[o_local][cls]

  const int rg = blockIdx.x;   // 0..1  (16 rows)
  const int og = blockIdx.y;   // 0..15 (16 o)
  const int b  = blockIdx.z;   // 0..63
  const int tid = threadIdx.x;
  const int lane = tid & 63;
  const int wv = tid >> 6;                       // wave 0..3
  const int w = lane & 31;
  const int rb = rg * 16 + wv * 4 + (lane >> 5) * 2;  // first of 2 out rows
  const bool wact = w < WW;

  if (tid < 144) atab[tid] = ptabA[og * 144 + tid];
  __syncthreads();

  // Own-column activations, rows rb-1 .. rb+2 (zero-padded outside image).
  const int wcl = wact ? w : (WW - 1);
  uint4 A[4][2];
#pragma unroll
  for (int i = 0; i < 4; ++i) {
    int rr = rb - 1 + i;
    bool v = (rr >= 0) && (rr < HH);
    const uint4* src =
        (const uint4*)(apack + ((size_t)(b * HWP + (v ? rr : 0) * WW + wcl)) * 8);
    uint4 lo = src[0], hi = src[1];
    if (!v) { lo = make_uint4(0, 0, 0, 0); hi = make_uint4(0, 0, 0, 0); }
    A[i][0] = lo;
    A[i][1] = hi;
  }
  // Pin the 32 activation words into VGPRs: opaque asm outputs cannot be
  // rematerialized by re-loading from apack inside the oi loop.
  {
    uint32* aw = (uint32*)A;
#pragma unroll
    for (int i = 0; i < 32; i += 4)
      asm volatile("" : "+v"(aw[i]), "+v"(aw[i + 1]), "+v"(aw[i + 2]),
                        "+v"(aw[i + 3]));
  }

  const int wc = (w == 0) ? 0 : (w == WW - 1 ? 2 : 1);
  const int r1v = rb + 1;
  const int hc0 = (rb == 0) ? 0 : (rb == HH - 1 ? 2 : 1);
  const int hc1 = (r1v == 0) ? 0 : (r1v == HH - 1 ? 2 : 1);
  const int cls0 = hc0 * 3 + wc;
  const int cls1 = hc1 * 3 + wc;

  const size_t obase = ((size_t)b * OO + og * 16) * HWP + (size_t)rb * WW + w;
  const bool st0 = wact && (rb < HH);
  const bool st1 = wact && (r1v < HH);

  for (int oi = 0; oi < 16; ++oi) {
    const int o = og * 16 + oi;
    const int wo = __builtin_amdgcn_readfirstlane(o * 72);
    const uint32* wt = wpack + wo;                // uniform -> s_load
    const uint4 pm = ((const uint4*)ptabP)[o];    // uniform -> s_load
    const float m = __uint_as_float(pm.x);

    // 6 independent fused popcount chains (ILP), 2 VALU per word-pair.
    uint32 T00 = 0, T01 = 0, T02 = 0, T10 = 0, T11 = 0, T12 = 0;
#pragma unroll
    for (int dh = 0; dh < 3; ++dh) {
      const uint32* a0 = (const uint32*)&A[dh][0];      // output row rb
      const uint32* a1 = (const uint32*)&A[dh + 1][0];  // output row rb+1
#pragma unroll
      for (int j = 0; j < 8; ++j) {
        const uint32 w0 = wt[(dh * 3 + 0) * 8 + j];
        const uint32 w1 = wt[(dh * 3 + 1) * 8 + j];
        const uint32 w2 = wt[(dh * 3 + 2) * 8 + j];
        const uint32 av0 = a0[j], av1 = a1[j];
        BCNT_ACC(T00, av0 ^ w0);
        BCNT_ACC(T01, av0 ^ w1);
        BCNT_ACC(T02, av0 ^ w2);
        BCNT_ACC(T10, av1 ^ w0);
        BCNT_ACC(T11, av1 ^ w1);
        BCNT_ACC(T12, av1 ^ w2);
      }
    }
    // Packed horizontal mix: row0 in low 16, row1 in high 16 (sums <= 768).
    uint32 pl = __shfl_up(T00 | (T10 << 16), 1);
    uint32 pr = __shfl_down(T02 | (T12 << 16), 1);
    if (w == 0)      pl = pm.y * 0x10001u;  // virtual zero column col0
    if (w == WW - 1) pr = pm.z * 0x10001u;  // virtual zero column col2
    uint32 tp = pl + (T01 | (T11 << 16)) + pr;  // carry-free packed add
    float r0 = fmaf(m, (float)(tp & 0xffffu), atab[oi * 9 + cls0]);
    float r1 = fmaf(m, (float)(tp >> 16), atab[oi * 9 + cls1]);
    if (st0) out[obase + (size_t)oi * HWP] = r0;
    if (st1) out[obase + (size_t)oi * HWP + WW] = r1;
  }
}

// ---------------------------------------------------------------------------
extern "C" void kernel_launch(void* const* d_in, const int* in_sizes, int n_in,
                              void* d_out, int out_size, void* d_ws,
                              size_t ws_size, hipStream_t stream) {
  const float* x     = (const float*)d_in[0];  // (64,256,28,28)
  const float* M     = (const float*)d_in[1];  // (256,256,3,3)
  const float* Z     = (const float*)d_in[2];  // (8,256,256,3,3)
  const float* alpha = (const float*)d_in[3];  // (256,1,1)
  const float* rv    = (const float*)d_in[4];  // (1,8)
  float* out = (float*)d_out;                  // (64,256,28,28)

  uint32* apack = (uint32*)d_ws;                         // 1,605,632 B
  uint32* wpack = (uint32*)((char*)d_ws + 1605632);      // 73,728 B
  float*  ptabA = (float*)((char*)d_ws + 1679360);       // 9,216 B
  uint32* ptabP = (uint32*)((char*)d_ws + 1688576);      // 4,096 B

  pack_x_kernel<<<dim3(4, 8, BB), 256, 0, stream>>>(x, apack);
  pack_w_kernel<<<dim3(256), 256, 0, stream>>>(M, Z, rv, alpha, wpack, ptabA,
                                               ptabP);
  conv_kernel<<<dim3(2, 16, BB), 256, 0, stream>>>(apack, wpack, ptabA, ptabP,
                                                   out);
}

// Round 2
// 185.686 us; speedup vs baseline: 1.0338x; 1.0103x over previous
//
#include <hip/hip_runtime.h>
#include <stdint.h>

typedef unsigned int uint32;

#define BB 64
#define CC 256
#define OO 256
#define HH 28
#define WW 28
#define HWP 784           // 28*28
#define NWT 589824        // 256*256*9

// ---------------------------------------------------------------------------
// Kernel 1: binarize & bit-pack activations. (unchanged — ~8.4 µs BW floor,
// reads coalesced; not the measured bottleneck)
// apack[b][p][j] (j=0..7): bit (c%32) of word j=c/32 set iff x[b][c][p] > 0.
// ---------------------------------------------------------------------------
__global__ __launch_bounds__(256) void pack_x_kernel(
    const float* __restrict__ x, uint32* __restrict__ apack) {
  int p = blockIdx.x * 256 + threadIdx.x;
  int j = blockIdx.y;
  int b = blockIdx.z;
  if (p >= HWP) return;
  const float* xp = x + ((size_t)(b * CC + j * 32) * HWP) + p;
  uint32 m = 0;
#pragma unroll
  for (int cc = 0; cc < 32; ++cc) {
    float v = xp[(size_t)cc * HWP];
    m |= ((uint32)(v > 0.0f)) << cc;
  }
  apack[((size_t)b * HWP + p) * 8 + j] = m;
}

// ---------------------------------------------------------------------------
// Kernel 2 (fused): binarize & bit-pack weights + per-o affine tables.
// (unchanged from R1 — passed, and the fusion's −3.4 µs dispatch saving held)
// ---------------------------------------------------------------------------
__global__ __launch_bounds__(256) void pack_w_kernel(
    const float* __restrict__ M, const float* __restrict__ Z,
    const float* __restrict__ rv, const float* __restrict__ alpha,
    uint32* __restrict__ wpack, float* __restrict__ ptabA,
    uint32* __restrict__ ptabP) {
  __shared__ float sacc[2304];
  __shared__ uint32 ww[72];
  const int o = blockIdx.x;
  const int tid = threadIdx.x;
  const size_t base = (size_t)o * 2304;

  float r[8];
#pragma unroll
  for (int k = 0; k < 8; ++k) r[k] = rv[k];

#pragma unroll
  for (int ii = 0; ii < 9; ++ii) {
    int i = tid + ii * 256;  // 2304 = 9*256 exactly, no bounds check
    float s = M[base + i];
#pragma unroll
    for (int k = 0; k < 8; ++k) s += r[k] * Z[(size_t)k * NWT + base + i];
    sacc[i] = s;
  }
  __syncthreads();

  if (tid < 72) {
    int tap = tid % 9;
    int j = tid / 9;
    uint32 m = 0;
#pragma unroll
    for (int cc = 0; cc < 32; ++cc) {
      float v = sacc[(j * 32 + cc) * 9 + tap];
      m |= ((uint32)(v > 0.0f)) << cc;
    }
    ww[tap * 8 + j] = m;
    wpack[(size_t)o * 72 + tap * 8 + j] = m;  // == (o*9+tap)*8+j
  }
  __syncthreads();

  if (tid == 0) {
    int pt[9];
#pragma unroll
    for (int t = 0; t < 9; ++t) {
      int s = 0;
#pragma unroll
      for (int j = 0; j < 8; ++j) s += __popc(ww[t * 8 + j]);
      pt[t] = s;
    }
    int row0 = pt[0] + pt[1] + pt[2], row2 = pt[6] + pt[7] + pt[8];
    int col0 = pt[0] + pt[3] + pt[6], col2 = pt[2] + pt[5] + pt[8];
    float a = alpha[o];
    const int nv[9] = {4, 6, 4, 6, 9, 6, 4, 6, 4};
    int S[9];
    S[0] = row0 + col0 - pt[0]; S[1] = row0; S[2] = row0 + col2 - pt[2];
    S[3] = col0;                S[4] = 0;    S[5] = col2;
    S[6] = row2 + col0 - pt[6]; S[7] = row2; S[8] = row2 + col2 - pt[8];
#pragma unroll
    for (int c = 0; c < 9; ++c)
      ptabA[o * 9 + c] = a * (float)(256 * nv[c] + 2 * S[c]);
    ptabP[o * 4 + 0] = __float_as_uint(-2.0f * a);
    ptabP[o * 4 + 1] = (uint32)col0;
    ptabP[o * 4 + 2] = (uint32)col2;
    ptabP[o * 4 + 3] = 0;
  }
}

// Guaranteed fused popcount-accumulate: T = bitcount(x) + T, one VALU inst.
#define BCNT_ACC(T, x) asm("v_bcnt_u32_b32 %0, %1, %0" : "+v"(T) : "v"(x))

// Load one dh-slab (3 taps x 8 words = 24 words = 96B contiguous) of o's
// weights into a uint4[6] register block. Byte offset o*288 + dh*96 is
// 16B-aligned. Issued BEFORE the compute that consumes the previous slab.
#define LOADSLAB(oi_, dh_, S)                                                  \
  {                                                                            \
    const uint4* wv_ = (const uint4*)(wpack +                                  \
        ((size_t)(og * 16 + (oi_)) * 72 + (dh_) * 24));                        \
    _Pragma("unroll") for (int t_ = 0; t_ < 6; ++t_) (S)[t_] = wv_[t_];        \
  }

// Accumulate one slab against activation rows dh_, dh_+1 (static index into
// A — macro, not function, so A indexing stays compile-time; rule #20).
// 8 j x (6 XOR + 6 BCNT) = 96 VALU = 192 cy of independent-chain work that
// hides the next slab's load latency (~120 cy L1 once wpack is hot).
#define ACC3(S, dh_)                                                           \
  {                                                                            \
    const uint32* sw_ = (const uint32*)(S);                                    \
    const uint32* a0_ = (const uint32*)&A[dh_][0];                             \
    const uint32* a1_ = (const uint32*)&A[(dh_) + 1][0];                       \
    _Pragma("unroll") for (int j_ = 0; j_ < 8; ++j_) {                         \
      const uint32 av0_ = a0_[j_], av1_ = a1_[j_];                             \
      const uint32 w0_ = sw_[j_], w1_ = sw_[8 + j_], w2_ = sw_[16 + j_];       \
      BCNT_ACC(T00, av0_ ^ w0_);                                               \
      BCNT_ACC(T01, av0_ ^ w1_);                                               \
      BCNT_ACC(T02, av0_ ^ w2_);                                               \
      BCNT_ACC(T10, av1_ ^ w0_);                                               \
      BCNT_ACC(T11, av1_ ^ w1_);                                               \
      BCNT_ACC(T12, av1_ ^ w2_);                                               \
    }                                                                          \
  }

// Packed horizontal mix + store (row0 low16 / row1 high16, sums <= 768 so
// the packed add is carry-free). Algebra identical to R5/R6 (absmax 0.5).
#define EPILOGUE(oi_, pm_)                                                     \
  {                                                                            \
    const float m_ = __uint_as_float((pm_).x);                                 \
    uint32 pl_ = __shfl_up(T00 | (T10 << 16), 1);                              \
    uint32 pr_ = __shfl_down(T02 | (T12 << 16), 1);                            \
    if (w == 0) pl_ = (pm_).y * 0x10001u;                                      \
    if (w == WW - 1) pr_ = (pm_).z * 0x10001u;                                 \
    const uint32 tp_ = pl_ + (T01 | (T11 << 16)) + pr_;                        \
    const float r0_ = fmaf(m_, (float)(tp_ & 0xffffu), atab[(oi_) * 9 + cls0]);\
    const float r1_ = fmaf(m_, (float)(tp_ >> 16), atab[(oi_) * 9 + cls1]);    \
    if (st0) out[obase + (size_t)(oi_) * HWP] = r0_;                           \
    if (st1) out[obase + (size_t)(oi_) * HWP + WW] = r1_;                      \
  }

// ---------------------------------------------------------------------------
// Kernel 3 (v6): binary conv, software-pipelined weight stream.
//
// R2 post-mortem of R1: the asm A-pin changed nothing (conv 81.7->80.7,
// VGPR_Count frozen at a bogus 24) -> the "A reload" theory is dead.
// Duration arithmetic: static VALU floor is ~33 µs; measured 80.7 µs at
// only 4 waves/SIMD. Diagnosis: the rolled oi loop front-loads all 72
// weight words + pm, then drains them immediately -> ~600 stall cycles per
// ~620 busy cycles each iteration, and 4 lockstep waves can't cover it.
//
// Fix: slab-granular double-buffered pipeline. Each oi = 3 slabs of 24
// words; slab s+1's loads issue before slab s's 192-cycle popcount block.
// After the first oi the 4.6 KB/block weight working set is L1-resident,
// so slab latency (~120 cy) < slab compute (192 cy) -> fully hidden.
// Registers: A 32 + Sa/Sb 48 + T 6 + misc ~ 106 < 128 cap of (256,4).
// ---------------------------------------------------------------------------
__global__ __launch_bounds__(256, 4) void conv_kernel(
    const uint32* __restrict__ apack, const uint32* __restrict__ wpack,
    const float* __restrict__ ptabA, const uint32* __restrict__ ptabP,
    float* __restrict__ out) {
  __shared__ float atab[16 * 9];  // A[o_local][cls]

  const int rg = blockIdx.x;   // 0..1  (16 rows)
  const int og = blockIdx.y;   // 0..15 (16 o)
  const int b  = blockIdx.z;   // 0..63
  const int tid = threadIdx.x;
  const int lane = tid & 63;
  const int wv = tid >> 6;                       // wave 0..3
  const int w = lane & 31;
  const int rb = rg * 16 + wv * 4 + (lane >> 5) * 2;  // first of 2 out rows
  const bool wact = w < WW;

  if (tid < 144) atab[tid] = ptabA[og * 144 + tid];
  __syncthreads();

  // Own-column activations, rows rb-1 .. rb+2 (zero-padded outside image).
  const int wcl = wact ? w : (WW - 1);
  uint4 A[4][2];
#pragma unroll
  for (int i = 0; i < 4; ++i) {
    int rr = rb - 1 + i;
    bool v = (rr >= 0) && (rr < HH);
    const uint4* src =
        (const uint4*)(apack + ((size_t)(b * HWP + (v ? rr : 0) * WW + wcl)) * 8);
    uint4 lo = src[0], hi = src[1];
    if (!v) { lo = make_uint4(0, 0, 0, 0); hi = make_uint4(0, 0, 0, 0); }
    A[i][0] = lo;
    A[i][1] = hi;
  }
  // Keep the 32 activation words pinned in VGPRs (harmless; proven neutral).
  {
    uint32* aw = (uint32*)A;
#pragma unroll
    for (int i = 0; i < 32; i += 4)
      asm volatile("" : "+v"(aw[i]), "+v"(aw[i + 1]), "+v"(aw[i + 2]),
                        "+v"(aw[i + 3]));
  }

  const int wc = (w == 0) ? 0 : (w == WW - 1 ? 2 : 1);
  const int r1v = rb + 1;
  const int hc0 = (rb == 0) ? 0 : (rb == HH - 1 ? 2 : 1);
  const int hc1 = (r1v == 0) ? 0 : (r1v == HH - 1 ? 2 : 1);
  const int cls0 = hc0 * 3 + wc;
  const int cls1 = hc1 * 3 + wc;

  const size_t obase = ((size_t)b * OO + og * 16) * HWP + (size_t)rb * WW + w;
  const bool st0 = wact && (rb < HH);
  const bool st1 = wact && (r1v < HH);

  uint4 Sa[6], Sb[6];
  uint32 T00, T01, T02, T10, T11, T12;

  LOADSLAB(0, 0, Sa);  // prologue: first slab in flight before the loop
  for (int ot = 0; ot < 16; ot += 2) {
    // pm for both oi of this pair: issued ~600 cy before first use.
    const uint4 pma = ((const uint4*)ptabP)[og * 16 + ot];
    const uint4 pmb = ((const uint4*)ptabP)[og * 16 + ot + 1];

    // ---- oi = ot ----  (enters with Sa = slab(ot,0))
    T00 = T01 = T02 = T10 = T11 = T12 = 0;
    LOADSLAB(ot, 1, Sb);       ACC3(Sa, 0);
    LOADSLAB(ot, 2, Sa);       ACC3(Sb, 1);
    LOADSLAB(ot + 1, 0, Sb);   ACC3(Sa, 2);
    EPILOGUE(ot, pma);

    // ---- oi = ot+1 ----  (enters with Sb = slab(ot+1,0))
    T00 = T01 = T02 = T10 = T11 = T12 = 0;
    LOADSLAB(ot + 1, 1, Sa);   ACC3(Sb, 0);
    LOADSLAB(ot + 1, 2, Sb);   ACC3(Sa, 1);
    {  // prefetch next pair's first slab; clamp keeps the last load in-bounds
      const int on = (ot + 2 < 16) ? (ot + 2) : 15;
      LOADSLAB(on, 0, Sa);
    }
    ACC3(Sb, 2);
    EPILOGUE(ot + 1, pmb);
  }
}

// ---------------------------------------------------------------------------
extern "C" void kernel_launch(void* const* d_in, const int* in_sizes, int n_in,
                              void* d_out, int out_size, void* d_ws,
                              size_t ws_size, hipStream_t stream) {
  const float* x     = (const float*)d_in[0];  // (64,256,28,28)
  const float* M     = (const float*)d_in[1];  // (256,256,3,3)
  const float* Z     = (const float*)d_in[2];  // (8,256,256,3,3)
  const float* alpha = (const float*)d_in[3];  // (256,1,1)
  const float* rv    = (const float*)d_in[4];  // (1,8)
  float* out = (float*)d_out;                  // (64,256,28,28)

  uint32* apack = (uint32*)d_ws;                         // 1,605,632 B
  uint32* wpack = (uint32*)((char*)d_ws + 1605632);      // 73,728 B
  float*  ptabA = (float*)((char*)d_ws + 1679360);       // 9,216 B
  uint32* ptabP = (uint32*)((char*)d_ws + 1688576);      // 4,096 B

  pack_x_kernel<<<dim3(4, 8, BB), 256, 0, stream>>>(x, apack);
  pack_w_kernel<<<dim3(256), 256, 0, stream>>>(M, Z, rv, alpha, wpack, ptabA,
                                               ptabP);
  conv_kernel<<<dim3(2, 16, BB), 256, 0, stream>>>(apack, wpack, ptabA, ptabP,
                                                   out);
}